// Round 4
// baseline (174.468 us; speedup 1.0000x reference)
//
#include <hip/hip_runtime.h>

#define BATCH 16
#define CH    16
#define HH    128
#define WW    128
#define NC    8            // n_convs
#define TR    8            // output rows per band
#define HR    (TR + 2)     // 10 halo rows
#define FW    (WW + 2)     // 130 halo cols
#define PLANE (HH * WW)

typedef float v2f __attribute__((ext_vector_type(2)));

// Per-element features: f0=silu(v), f1=tanh(v), f2=2t^2 (=T2+1), f3=T3=4t^3-3t.
// bias_j = sum_i (W0 - W2)[j,i] absorbs T0 and the +1 shift of f2, so features
// are exactly (0,0,0,0) at v=0 -> zero padding handled by feat(0)=0.
// acc kept at 32 VGPRs (v2f[4][4]); j's processed in pairs to enable v_pk_fma_f32.
__global__ __launch_bounds__(256, 4)
void kan_conv_kernel(const float* __restrict__ x,
                     const float* __restrict__ cheby,   // (8,9,4)
                     const float* __restrict__ bwt,     // (8,9)
                     const float* __restrict__ scl,     // (8,9)
                     float* __restrict__ out)           // (16,128,128,128)
{
    __shared__ float4 feat[HR][FW];      // 20,800 B
    __shared__ v2f    wgt2[9][4][4];     // [tap][feature][jpair] = (w_j0, w_j1)
    __shared__ v2f    bias2[4];

    const int tid  = threadIdx.x;        // 0..255
    const int band = blockIdx.x * TR;
    const int bz   = blockIdx.y;         // plane = b*CH + c

    // ---- stage weights as j-pairs: feature 0=bw, 1=W1, 2=W2, 3=W3 ----
    if (tid < 9 * 4 * 4) {
        int tap = tid >> 4, k = (tid >> 2) & 3, jp = tid & 3;
        int j0 = jp * 2, j1 = j0 + 1;
        v2f w;
        if (k == 0) {
            w.x = bwt[j0 * 9 + tap];
            w.y = bwt[j1 * 9 + tap];
        } else {
            w.x = cheby[(j0 * 9 + tap) * 4 + k] * scl[j0 * 9 + tap];
            w.y = cheby[(j1 * 9 + tap) * 4 + k] * scl[j1 * 9 + tap];
        }
        wgt2[tap][k][jp] = w;
    } else if (tid >= 144 && tid < 148) {
        int jp = tid - 144;
        v2f b; b.x = 0.f; b.y = 0.f;
        #pragma unroll
        for (int i = 0; i < 9; ++i) {
            int j0 = jp * 2, j1 = j0 + 1;
            b.x += (cheby[(j0 * 9 + i) * 4 + 0] - cheby[(j0 * 9 + i) * 4 + 2]) * scl[j0 * 9 + i];
            b.y += (cheby[(j1 * 9 + i) * 4 + 0] - cheby[(j1 * 9 + i) * 4 + 2]) * scl[j1 * 9 + i];
        }
        bias2[jp] = b;
    }

    // ---- stage halo band: one element/thread, 16B/lane LDS writes (no conflict) ----
    const float* xp = x + (size_t)bz * PLANE;
    for (int idx = tid; idx < HR * FW; idx += 256) {
        int row = idx / FW;
        int col = idx - row * FW;
        int gh  = band + row - 1;
        int gw  = col - 1;
        float v = 0.f;
        if ((unsigned)gh < (unsigned)HH && (unsigned)gw < (unsigned)WW)
            v = xp[gh * WW + gw];                              // coalesced dword
        float e1 = __expf(v);
        float e2 = e1 * e1;                                    // exp(2v)
        float sg = 1.f - __builtin_amdgcn_rcpf(1.f + e1);      // sigmoid(v)
        float t  = 1.f - 2.f * __builtin_amdgcn_rcpf(e2 + 1.f);// tanh(v)
        float f2 = 2.f * t * t;                                // T2 + 1
        float f3 = 2.f * t * (f2 - 1.f) - t;                   // T3
        feat[row][col] = make_float4(v * sg, t, f2, f3);
    }
    __syncthreads();

    // ---- conv: thread owns col c, 4 CONSECUTIVE rows rb..rb+3 ----
    // 6 feature rows per dc cover all 3 dr taps: 18 ds_read_b128/thread total.
    const int c  = tid & 127;            // 0..127
    const int rb = (tid >> 7) * 4;       // 0 or 4

    v2f acc[4][4];                       // [row][jpair] = 32 VGPRs
    #pragma unroll
    for (int r = 0; r < 4; ++r)
        #pragma unroll
        for (int jp = 0; jp < 4; ++jp)
            acc[r][jp] = bias2[jp];

    #pragma unroll
    for (int dc = 0; dc < 3; ++dc) {
        float4 f[6];
        #pragma unroll
        for (int rr = 0; rr < 6; ++rr)
            f[rr] = feat[rb + rr][c + dc];          // 16B/lane: conflict-free
        #pragma unroll
        for (int dr = 0; dr < 3; ++dr) {
            const int tap = dr * 3 + dc;
            #pragma unroll
            for (int jp = 0; jp < 4; ++jp) {
                v2f w0 = wgt2[tap][0][jp];          // uniform broadcast reads
                v2f w1 = wgt2[tap][1][jp];
                v2f w2 = wgt2[tap][2][jp];
                v2f w3 = wgt2[tap][3][jp];
                #pragma unroll
                for (int r = 0; r < 4; ++r) {
                    float4 fv = f[r + dr];
                    acc[r][jp] += w0 * fv.x;        // v_pk_fma_f32 candidates
                    acc[r][jp] += w1 * fv.y;
                    acc[r][jp] += w2 * fv.z;
                    acc[r][jp] += w3 * fv.w;
                }
            }
        }
    }

    // ---- store: 64 consecutive floats per wave-store, non-temporal ----
    float* op = out + (size_t)(bz * NC) * PLANE + (size_t)(band + rb) * WW + c;
    #pragma unroll
    for (int jp = 0; jp < 4; ++jp)
        #pragma unroll
        for (int r = 0; r < 4; ++r) {
            __builtin_nontemporal_store(acc[r][jp].x, op + (size_t)(jp * 2)     * PLANE + r * WW);
            __builtin_nontemporal_store(acc[r][jp].y, op + (size_t)(jp * 2 + 1) * PLANE + r * WW);
        }
}

extern "C" void kernel_launch(void* const* d_in, const int* in_sizes, int n_in,
                              void* d_out, int out_size, void* d_ws, size_t ws_size,
                              hipStream_t stream) {
    const float* x     = (const float*)d_in[0];
    const float* cheby = (const float*)d_in[1];
    const float* bwt   = (const float*)d_in[2];
    const float* scl   = (const float*)d_in[3];
    float* out = (float*)d_out;

    dim3 grid(HH / TR, BATCH * CH);      // 16 x 256 = 4096 blocks
    dim3 block(256);
    hipLaunchKernelGGL(kan_conv_kernel, grid, block, 0, stream, x, cheby, bwt, scl, out);
}